// Round 1
// baseline (27.783 us; speedup 1.0000x reference)
//
#include <hip/hip_runtime.h>

#define M_PROF 128
#define KSTATES 258            // 2*(M+1)
#define NSTEP 774              // (M+1)*3*2 per-batch stride of insert/delete logits
#define NEG_INF_F (-1.0e32f)   // -1.0/EPS with EPS=1e-32

// ---------------------------------------------------------------------------
// Kernel 0: per-batch inclusive prefix sums
//   psi[b][x] = sum_{t<=x} insert[b,t,2,0]
//   psd[b][x] = sum_{t<=x} delete[b,t,2,1]
// ---------------------------------------------------------------------------
__global__ void prefix_kernel(const float* __restrict__ ins,
                              const float* __restrict__ del,
                              float* __restrict__ psi,
                              float* __restrict__ psd) {
    int t = threadIdx.x;           // 64 threads: 0..31 -> SI, 32..63 -> SD
    int b = t & 31;
    const float* src = (t < 32) ? (ins + b * NSTEP + 4)   // [x,2,0] -> x*6+4
                                : (del + b * NSTEP + 5);  // [x,2,1] -> x*6+5
    float* dst = (t < 32) ? (psi + b * (M_PROF + 1)) : (psd + b * (M_PROF + 1));
    float s = 0.0f;
    for (int x = 0; x <= M_PROF; ++x) {
        s += src[x * 6];
        dst[x] = s;
    }
}

// ---------------------------------------------------------------------------
// Shared per-entry evaluator. (a,g) identify the source row; f = kp column.
// ---------------------------------------------------------------------------
__device__ __forceinline__ float profile_entry(
    const float* __restrict__ ins_b, const float* __restrict__ del_b,
    const float* __restrict__ psi_b, const float* __restrict__ psd_b,
    int a, float ins_a0, float ins_a1, float del_a0, float del_a1,
    float psi_a, float psd_a, int f, bool special_row) {
    int mp  = f >> 1;
    int gp0 = f & 1;  // 1 <=> gp == 0 (kp odd)
    if (mp == a) {
        // case A / C
        return gp0 ? (ins_a0 + (a < M_PROF ? del_a0 : 0.0f)) : ins_a1;
    } else if (mp > a) {
        // case B / D: run from a+1 .. mp-1 via prefix sums
        float base = ins_a0 + del_a1 + (psi_b[mp - 1] - psi_a)
                                     + (psd_b[mp - 1] - psd_a);
        if (gp0)
            return base + ins_b[mp * 6 + 4] + (mp < M_PROF ? del_b[mp * 6 + 4] : 0.0f);
        else
            return base + ins_b[mp * 6 + 5];
    } else {
        // null region; the (k=257, kp=257) cell is excluded from null -> 0
        return (special_row && f == (KSTATES - 1)) ? 0.0f : NEG_INF_F;
    }
}

// ---------------------------------------------------------------------------
// Kernel 1: transition_logits[b][l][f]
// ---------------------------------------------------------------------------
__global__ void trans_kernel(const float* __restrict__ ins,
                             const float* __restrict__ del,
                             const float* __restrict__ psi,
                             const float* __restrict__ psd,
                             float* __restrict__ out) {
    int l = blockIdx.x;
    int b = blockIdx.y;
    const float* ins_b = ins + b * NSTEP;
    const float* del_b = del + b * NSTEP;
    const float* psi_b = psi + b * (M_PROF + 1);
    const float* psd_b = psd + b * (M_PROF + 1);

    int g = 1 - (l & 1);                 // l odd -> g=0, l even -> g=1
    int a = (l >> 1) + (l & 1);          // a = m + 1 - g  (can be M+1 when l==257)
    int ac = (a <= M_PROF) ? a : M_PROF; // clamped index for (unused-in-else) loads

    float ins_a0 = ins_b[ac * 6 + g * 2 + 0];
    float ins_a1 = ins_b[ac * 6 + g * 2 + 1];
    float del_a0 = del_b[ac * 6 + g * 2 + 0];
    float del_a1 = del_b[ac * 6 + g * 2 + 1];
    float psi_a  = psi_b[ac];
    float psd_a  = psd_b[ac];
    bool special = (l == KSTATES - 1);

    float* orow = out + ((size_t)b * KSTATES + l) * KSTATES;
    for (int f = threadIdx.x; f < KSTATES; f += blockDim.x) {
        orow[f] = profile_entry(ins_b, del_b, psi_b, psd_b, a,
                                ins_a0, ins_a1, del_a0, del_a1,
                                psi_a, psd_a, f, special);
    }
}

// ---------------------------------------------------------------------------
// Kernel 2: initial_logits[b][f]  (same formula at m=-1, g=0 -> a=0)
// ---------------------------------------------------------------------------
__global__ void init_kernel(const float* __restrict__ ins,
                            const float* __restrict__ del,
                            const float* __restrict__ psi,
                            const float* __restrict__ psd,
                            float* __restrict__ out) {
    int b = blockIdx.x;
    int f = threadIdx.x;
    if (f >= KSTATES) return;
    const float* ins_b = ins + b * NSTEP;
    const float* del_b = del + b * NSTEP;
    const float* psi_b = psi + b * (M_PROF + 1);
    const float* psd_b = psd + b * (M_PROF + 1);

    float ins_a0 = ins_b[0];  // insert[b,0,0,0]
    float ins_a1 = ins_b[1];  // insert[b,0,0,1]
    float del_a0 = del_b[0];  // delete[b,0,0,0]
    float del_a1 = del_b[1];  // delete[b,0,0,1]
    float psi_a  = psi_b[0];
    float psd_a  = psd_b[0];

    out[b * KSTATES + f] = profile_entry(ins_b, del_b, psi_b, psd_b, /*a=*/0,
                                         ins_a0, ins_a1, del_a0, del_a1,
                                         psi_a, psd_a, f, /*special=*/false);
}

// ---------------------------------------------------------------------------
// Kernel 3: observation_logits[b][kp][o] = LSE_j(row[j] + sub[b,j,o])
//   kp odd  (g=0) -> row = precursor_seq_logits[b, kp>>1, :]
//   kp even (g=1) -> row = insert_seq_logits[b, kp>>1, :]
// ---------------------------------------------------------------------------
__global__ void obs_kernel(const float* __restrict__ pre,
                           const float* __restrict__ insq,
                           const float* __restrict__ sub,
                           float* __restrict__ out) {
    __shared__ float s_sub[400];  // sub[b] : 20 x 20
    int b = blockIdx.x;
    for (int t = threadIdx.x; t < 400; t += blockDim.x)
        s_sub[t] = sub[b * 400 + t];
    __syncthreads();

    int idx = blockIdx.y * blockDim.x + threadIdx.x;   // over 258*20 = 5160
    if (idx >= KSTATES * 20) return;
    int kp = idx / 20;
    int o  = idx - kp * 20;
    int mrow = kp >> 1;
    const float* row = (kp & 1) ? (pre  + ((size_t)b * (M_PROF + 1) + mrow) * 20)
                                : (insq + ((size_t)b * (M_PROF + 1) + mrow) * 20);
    float v[20];
    float mx = -3.0e38f;
#pragma unroll
    for (int j = 0; j < 20; ++j) {
        v[j] = row[j] + s_sub[j * 20 + o];
        mx = fmaxf(mx, v[j]);
    }
    float s = 0.0f;
#pragma unroll
    for (int j = 0; j < 20; ++j) s += expf(v[j] - mx);
    out[((size_t)b * KSTATES + kp) * 20 + o] = mx + logf(s);
}

// ---------------------------------------------------------------------------
extern "C" void kernel_launch(void* const* d_in, const int* in_sizes, int n_in,
                              void* d_out, int out_size, void* d_ws, size_t ws_size,
                              hipStream_t stream) {
    const float* pre  = (const float*)d_in[0];  // precursor_seq_logits (32,129,20)
    const float* insq = (const float*)d_in[1];  // insert_seq_logits    (32,129,20)
    const float* ins  = (const float*)d_in[2];  // insert_logits        (32,129,3,2)
    const float* del  = (const float*)d_in[3];  // delete_logits        (32,129,3,2)
    const float* sub  = (const float*)d_in[4];  // substitute_logits    (32,20,20)
    // d_in[5..12] = transfer tensors: structure is computed analytically, not read.

    float* out = (float*)d_out;
    float* out_init  = out;                                   // 32*258
    float* out_trans = out + 32 * KSTATES;                    // 32*258*258
    float* out_obs   = out_trans + (size_t)32 * KSTATES * KSTATES;  // 32*258*20

    float* psi = (float*)d_ws;                 // 32*129 floats
    float* psd = psi + 32 * (M_PROF + 1);      // 32*129 floats

    hipLaunchKernelGGL(prefix_kernel, dim3(1), dim3(64), 0, stream,
                       ins, del, psi, psd);
    hipLaunchKernelGGL(trans_kernel, dim3(KSTATES, 32), dim3(256), 0, stream,
                       ins, del, psi, psd, out_trans);
    hipLaunchKernelGGL(init_kernel, dim3(32), dim3(320), 0, stream,
                       ins, del, psi, psd, out_init);
    hipLaunchKernelGGL(obs_kernel, dim3(32, 21), dim3(256), 0, stream,
                       pre, insq, sub, out_obs);
}

// Round 2
// 11.602 us; speedup vs baseline: 2.3946x; 2.3946x over previous
//
#include <hip/hip_runtime.h>

#define MM 128                 // M
#define KS 258                 // 2*(M+1)
#define NSTEP 774              // (M+1)*3*2 per-batch stride of insert/delete logits
#define NEG_INF_F (-1.0e32f)   // -1.0/EPS, EPS = 1e-32

// Output layout in d_out (floats):
//   init  : [0, 32*258)
//   trans : [8256, 8256 + 32*258*258)
//   obs   : [2138304, 2138304 + 32*258*20)
#define TRANS_BASE 8256
#define OBS_BASE   2138304

// One fused kernel. blockIdx.y = batch b. blockIdx.x = chunk:
//   chunks 0..32  : transition rows (8 rows/chunk; pseudo-row 258 = initial)
//   chunks 33..53 : observation outputs (256 per chunk over 258*20=5160)
__global__ __launch_bounds__(256) void profile_fused_kernel(
    const float* __restrict__ pre,   // (32,129,20)
    const float* __restrict__ insq,  // (32,129,20)
    const float* __restrict__ ins,   // (32,129,3,2)
    const float* __restrict__ del,   // (32,129,3,2)
    const float* __restrict__ sub,   // (32,20,20)
    float* __restrict__ out)
{
    const int b   = blockIdx.y;
    const int chk = blockIdx.x;
    const int tid = threadIdx.x;

    if (chk < 33) {
        // ---------------- transition / initial rows ----------------
        __shared__ float2 ps[129];           // inclusive prefix {sum i20, sum d21}
        __shared__ float  i20[129], i21[129], d20[129];
        __shared__ float  rp[8][6];          // {ins_a0, ins_a1, del_a0, del_a1, psi_a, psd_a}
        __shared__ int    roff[8];           // output base (elements), -1 = idle
        __shared__ int    rmeta[8];          // (a<<1) | special

        const float* ins_b = ins + b * NSTEP;
        const float* del_b = del + b * NSTEP;

        if (tid < 129) {
            float a0 = ins_b[tid * 6 + 4];   // ins[b,x,2,0]
            float d1 = del_b[tid * 6 + 5];   // del[b,x,2,1]
            i20[tid] = a0;
            i21[tid] = ins_b[tid * 6 + 5];   // ins[b,x,2,1]
            d20[tid] = del_b[tid * 6 + 4];   // del[b,x,2,0]
            ps[tid]  = make_float2(a0, d1);
        }
        __syncthreads();
        // Hillis-Steele inclusive scan over 129 elements (both arrays packed)
        for (int off = 1; off < 129; off <<= 1) {
            float2 add = make_float2(0.f, 0.f);
            if (tid < 129 && tid >= off) add = ps[tid - off];
            __syncthreads();
            if (tid < 129) { float2 v = ps[tid]; v.x += add.x; v.y += add.y; ps[tid] = v; }
            __syncthreads();
        }

        // per-row parameters
        if (tid < 8) {
            int row = chk * 8 + tid;
            if (row <= 258) {
                int a, goff, ooff, special = 0;
                if (row == 258) {            // initial row: m=-1, g=0 -> a=0
                    a = 0; goff = 0;
                    ooff = b * KS;
                } else {
                    int g = 1 - (row & 1);           // row odd -> g=0
                    a = (row >> 1) + (row & 1);      // m + 1 - g (129 when row==257)
                    int ac = (a <= MM) ? a : MM;
                    goff = ac * 6 + g * 2;
                    ooff = TRANS_BASE + b * (KS * KS) + row * KS;
                    special = (row == 257);
                }
                int ac = (a <= MM) ? a : MM;
                rp[tid][0] = ins_b[goff];
                rp[tid][1] = ins_b[goff + 1];
                rp[tid][2] = del_b[goff];
                rp[tid][3] = del_b[goff + 1];
                rp[tid][4] = ps[ac].x;
                rp[tid][5] = ps[ac].y;
                roff[tid]  = ooff;
                rmeta[tid] = (a << 1) | special;
            } else {
                roff[tid] = -1;
            }
        }
        __syncthreads();

        // 8 rows x 129 column-pairs; pair j covers columns (2j, 2j+1) sharing mp=j
        for (int e = tid; e < 8 * 129; e += 256) {
            int r = e / 129;
            int j = e - r * 129;
            int ooff = roff[r];
            if (ooff < 0) continue;
            int meta = rmeta[r];
            int a    = meta >> 1;
            float ve, vo;
            if (j == a) {
                // mp==a: gp==1 (even col) -> ins_a1 ; gp==0 (odd col) -> ins_a0 [+ del_a0]
                ve = rp[r][1];
                vo = rp[r][0] + ((a < MM) ? rp[r][2] : 0.0f);
            } else if (j > a) {
                // a < mp <= M: base + run-sum via prefix difference
                float base = rp[r][0] + rp[r][3]
                           + (ps[j - 1].x - rp[r][4])
                           + (ps[j - 1].y - rp[r][5]);
                ve = base + i21[j];
                vo = base + i20[j] + ((j < MM) ? d20[j] : 0.0f);
            } else {
                ve = NEG_INF_F;
                vo = ((meta & 1) && j == 128) ? 0.0f : NEG_INF_F;  // (257,257) cell
            }
            *(float2*)(out + ooff + 2 * j) = make_float2(ve, vo);
        }
    } else {
        // ---------------- observation logits ----------------
        __shared__ float s_sub[400];         // sub[b] : 20 x 20
        for (int t = tid; t < 400; t += 256) s_sub[t] = sub[b * 400 + t];
        __syncthreads();

        int idx = (chk - 33) * 256 + tid;    // over 258*20 = 5160
        if (idx < KS * 20) {
            int kp = idx / 20;
            int o  = idx - kp * 20;
            int mrow = kp >> 1;
            const float* row = (kp & 1) ? (pre  + (b * (MM + 1) + mrow) * 20)
                                        : (insq + (b * (MM + 1) + mrow) * 20);
            float v[20];
            float mx = -3.0e38f;
#pragma unroll
            for (int j = 0; j < 20; ++j) {
                v[j] = row[j] + s_sub[j * 20 + o];
                mx = fmaxf(mx, v[j]);
            }
            float s = 0.0f;
#pragma unroll
            for (int j = 0; j < 20; ++j) s += expf(v[j] - mx);
            out[OBS_BASE + (b * KS + kp) * 20 + o] = mx + logf(s);
        }
    }
}

extern "C" void kernel_launch(void* const* d_in, const int* in_sizes, int n_in,
                              void* d_out, int out_size, void* d_ws, size_t ws_size,
                              hipStream_t stream) {
    const float* pre  = (const float*)d_in[0];  // precursor_seq_logits
    const float* insq = (const float*)d_in[1];  // insert_seq_logits
    const float* ins  = (const float*)d_in[2];  // insert_logits
    const float* del  = (const float*)d_in[3];  // delete_logits
    const float* sub  = (const float*)d_in[4];  // substitute_logits
    // d_in[5..12]: transfer tensors — structure computed analytically, never read.

    hipLaunchKernelGGL(profile_fused_kernel, dim3(54, 32), dim3(256), 0, stream,
                       pre, insq, ins, del, sub, (float*)d_out);
}

// Round 3
// 11.598 us; speedup vs baseline: 2.3955x; 1.0004x over previous
//
#include <hip/hip_runtime.h>

#define MM 128                 // M
#define KS 258                 // 2*(M+1)
#define NSTEP 774              // (M+1)*3*2 per-batch stride of insert/delete logits
#define NEG_INF_F (-1.0e32f)   // -1.0/EPS, EPS = 1e-32

// Output layout in d_out (floats):
//   init  : [0, 32*258)
//   trans : [8256, 8256 + 32*258*258)
//   obs   : [2138304, 2138304 + 32*258*20)
#define TRANS_BASE 8256
#define OBS_BASE   2138304

// One fused kernel. blockIdx.y = batch b. blockIdx.x = chunk:
//   chunks 0..31  : transition rows chk*8 .. chk*8+7, stored as 516 float4s
//   chunk  32     : transition rows 256,257 (129 float4s) + initial row (float2s)
//   chunks 33..53 : observation outputs (256 per chunk over 258*20=5160)
__global__ __launch_bounds__(256) void profile_fused_kernel(
    const float* __restrict__ pre,   // (32,129,20)
    const float* __restrict__ insq,  // (32,129,20)
    const float* __restrict__ ins,   // (32,129,3,2)
    const float* __restrict__ del,   // (32,129,3,2)
    const float* __restrict__ sub,   // (32,20,20)
    float* __restrict__ out)
{
    const int b   = blockIdx.y;
    const int chk = blockIdx.x;
    const int tid = threadIdx.x;

    if (chk < 33) {
        // ---------------- transition / initial rows ----------------
        __shared__ float2 ps[129];          // inclusive prefix {sum ins[,2,0], sum del[,2,1]}
        __shared__ float  i20[129], i21[129], d20[129];
        __shared__ float4 rp[9];            // {ins_a0, ins_a1, del_a0, del_a1} per row slot
        __shared__ int    rmeta[9];         // (a<<1) | special
        __shared__ float2 s_tot0, s_e128;

        const float* ins_b = ins + b * NSTEP;
        const float* del_b = del + b * NSTEP;

        // element loads (registers + LDS side arrays)
        float2 v = make_float2(0.f, 0.f);
        if (tid < 129) {
            float a0 = ins_b[tid * 6 + 4];  // ins[b,x,2,0]
            float d1 = del_b[tid * 6 + 5];  // del[b,x,2,1]
            i20[tid] = a0;
            i21[tid] = ins_b[tid * 6 + 5];  // ins[b,x,2,1]
            d20[tid] = del_b[tid * 6 + 4];  // del[b,x,2,0]
            v = make_float2(a0, d1);
        }

        // per-row params (independent of the scan)
        {
            int nrows = (chk < 32) ? 8 : 3;   // chunk 32: slots {row256, row257, init}
            if (tid < nrows) {
                int a, goff, special = 0;
                if (chk == 32 && tid == 2) {          // initial row: m=-1,g=0 -> a=0
                    a = 0; goff = 0;
                } else {
                    int row = chk * 8 + tid;
                    int g = 1 - (row & 1);            // row odd -> g=0
                    a = (row >> 1) + (row & 1);       // m + 1 - g (129 when row==257)
                    int ac = (a <= MM) ? a : MM;
                    goff = ac * 6 + g * 2;
                    special = (row == 257);
                }
                rp[tid] = make_float4(ins_b[goff], ins_b[goff + 1],
                                      del_b[goff], del_b[goff + 1]);
                rmeta[tid] = (a << 1) | special;
            }
        }

        // wave-shuffle inclusive scan over elements 0..127 (2 waves)
        if (tid < 128) {
            int lane = tid & 63;
#pragma unroll
            for (int d = 1; d < 64; d <<= 1) {
                float ox = __shfl_up(v.x, d);
                float oy = __shfl_up(v.y, d);
                if (lane >= d) { v.x += ox; v.y += oy; }
            }
            if (tid == 63) s_tot0 = v;
        }
        if (tid == 128) s_e128 = v;
        __syncthreads();
        if (tid < 128) {
            if (tid >= 64) { v.x += s_tot0.x; v.y += s_tot0.y; }
            ps[tid] = v;
            if (tid == 127)
                ps[128] = make_float2(v.x + s_e128.x, v.y + s_e128.y);
        }
        __syncthreads();

        // per-element evaluator (f = column 0..257, r = row slot)
        auto entry = [&](int r, int f) -> float {
            int meta = rmeta[r];
            int a    = meta >> 1;
            int mp   = f >> 1;
            int odd  = f & 1;                 // odd <=> gp == 0
            float4 p = rp[r];
            if (mp == a)
                return odd ? (p.x + ((a < MM) ? p.z : 0.0f)) : p.y;
            if (mp > a) {
                float2 pj = ps[mp - 1], pa = ps[a];
                float base = p.x + p.w + (pj.x - pa.x) + (pj.y - pa.y);
                return odd ? (base + i20[mp] + ((mp < MM) ? d20[mp] : 0.0f))
                           : (base + i21[mp]);
            }
            return ((meta & 1) && f == (KS - 1)) ? 0.0f : NEG_INF_F;
        };

        if (chk < 32) {
            // 8 rows = 2064 floats = 516 float4s, 16B-aligned contiguous region
            float* obase = out + TRANS_BASE + b * (KS * KS) + chk * 2064;
            for (int q = tid; q < 516; q += 256) {
                int idx = q * 4;
                int r = idx / KS;
                int f = idx - r * KS;
                float v0 = entry(r, f); if (++f == KS) { f = 0; ++r; }
                float v1 = entry(r, f); if (++f == KS) { f = 0; ++r; }
                float v2 = entry(r, f); if (++f == KS) { f = 0; ++r; }
                float v3 = entry(r, f);
                *(float4*)(obase + idx) = make_float4(v0, v1, v2, v3);
            }
        } else {
            // rows 256,257: 516 floats = 129 float4s; then init row as 129 float2s
            float* obase = out + TRANS_BASE + b * (KS * KS) + 256 * KS;
            float* ibase = out + b * KS;
            for (int e = tid; e < 258; e += 256) {
                if (e < 129) {
                    int idx = e * 4;
                    int r = idx / KS;            // 0 -> row 256, 1 -> row 257
                    int f = idx - r * KS;
                    float v0 = entry(r, f); if (++f == KS) { f = 0; ++r; }
                    float v1 = entry(r, f); if (++f == KS) { f = 0; ++r; }
                    float v2 = entry(r, f); if (++f == KS) { f = 0; ++r; }
                    float v3 = entry(r, f);
                    *(float4*)(obase + idx) = make_float4(v0, v1, v2, v3);
                } else {
                    int j = e - 129;             // init row columns (2j, 2j+1)
                    float ve = entry(2, 2 * j);
                    float vo = entry(2, 2 * j + 1);
                    *(float2*)(ibase + 2 * j) = make_float2(ve, vo);
                }
            }
        }
    } else {
        // ---------------- observation logits ----------------
        __shared__ float s_sub[400];         // sub[b] : 20 x 20
        for (int t = tid; t < 400; t += 256) s_sub[t] = sub[b * 400 + t];
        __syncthreads();

        int idx = (chk - 33) * 256 + tid;    // over 258*20 = 5160
        if (idx < KS * 20) {
            int kp = idx / 20;
            int o  = idx - kp * 20;
            int mrow = kp >> 1;
            const float* row = (kp & 1) ? (pre  + (b * (MM + 1) + mrow) * 20)
                                        : (insq + (b * (MM + 1) + mrow) * 20);
            float v[20];
            float mx = -3.0e38f;
#pragma unroll
            for (int j = 0; j < 20; ++j) {
                v[j] = row[j] + s_sub[j * 20 + o];
                mx = fmaxf(mx, v[j]);
            }
            float s = 0.0f;
#pragma unroll
            for (int j = 0; j < 20; ++j) s += expf(v[j] - mx);
            out[OBS_BASE + (b * KS + kp) * 20 + o] = mx + logf(s);
        }
    }
}

extern "C" void kernel_launch(void* const* d_in, const int* in_sizes, int n_in,
                              void* d_out, int out_size, void* d_ws, size_t ws_size,
                              hipStream_t stream) {
    const float* pre  = (const float*)d_in[0];  // precursor_seq_logits
    const float* insq = (const float*)d_in[1];  // insert_seq_logits
    const float* ins  = (const float*)d_in[2];  // insert_logits
    const float* del  = (const float*)d_in[3];  // delete_logits
    const float* sub  = (const float*)d_in[4];  // substitute_logits
    // d_in[5..12]: transfer tensors — structure computed analytically, never read.

    hipLaunchKernelGGL(profile_fused_kernel, dim3(54, 32), dim3(256), 0, stream,
                       pre, insq, ins, del, sub, (float*)d_out);
}